// Round 13
// baseline (2443.801 us; speedup 1.0000x reference)
//
#include <hip/hip_runtime.h>
#include <hip/hip_bf16.h>
#include <math.h>

#define MQ   65536
#define OUTD 128

typedef __attribute__((ext_vector_type(8))) short bf16x8;
typedef __attribute__((ext_vector_type(4))) short bf16x4;
typedef __attribute__((ext_vector_type(4))) float f32x4;

// ws byte offsets (bf16 weights + folded pos params)
#define WS_QKV   0        // 2*192*64 bf16 = 49152B
#define WS_AOW   49152    // 2*64*64       = 16384B
#define WS_F1W   65536    // 2*128*64      = 32768B
#define WS_F2W   98304    // 2*64*128      = 32768B
#define WS_PW2   131072   // 64*32         = 4096B
#define WS_W1F   135168   // 32*3 f32      = 384B
#define WS_PBF   135552   // 32 f32        = 128B

__device__ __forceinline__ unsigned short f2bf(float f) {
  unsigned u = __float_as_uint(f);
  u = (u + 0x7FFFu + ((u >> 16) & 1u)) >> 16;   // RTN
  return (unsigned short)u;
}

__device__ __forceinline__ f32x4 mfma16(bf16x8 a, bf16x8 b, f32x4 c) {
  return __builtin_amdgcn_mfma_f32_16x16x32_bf16(a, b, c, 0, 0, 0);
}

__device__ __forceinline__ unsigned pk2(float a, float b) {
  union { __hip_bfloat162 h; unsigned u; } c;
  float2 p; p.x = a; p.y = b;
  c.h = __float22bfloat162_rn(p);
  return c.u;
}

__device__ __forceinline__ bf16x4 pack4(f32x4 v) {
  union { unsigned u[2]; bf16x4 s; } c;
  c.u[0] = pk2(v[0], v[1]);
  c.u[1] = pk2(v[2], v[3]);
  return c.s;
}

__device__ __forceinline__ bf16x8 pack8(const float* v) {
  union { unsigned u[4]; bf16x8 s; } c;
#pragma unroll
  for (int i = 0; i < 4; i++) c.u[i] = pk2(v[2*i], v[2*i+1]);
  return c.s;
}

// Opaque compiler fence: pins same-wave LDS read/write ordering across mixed
// access types (LDS is in-order per wave at HW level).
__device__ __forceinline__ void cfence() { asm volatile("" ::: "memory"); }

// ---------------- weight conversion prologue (unchanged, round-2-verified) ----------------
extern "C" __global__ __launch_bounds__(256)
void convert_weights(const float* __restrict__ qkv_w, const float* __restrict__ aow,
                     const float* __restrict__ f1w,  const float* __restrict__ f2w,
                     const float* __restrict__ pw2,  const float* __restrict__ pw1,
                     const float* __restrict__ png,  const float* __restrict__ pnb,
                     const float* __restrict__ pnm,  const float* __restrict__ pnv,
                     unsigned char* __restrict__ ws) {
  int i = blockIdx.x * 256 + threadIdx.x;
  if (i < 24576) {
    ((unsigned short*)(ws + WS_QKV))[i] = f2bf(qkv_w[i]);
  } else if (i < 32768) {
    int j = i - 24576; ((unsigned short*)(ws + WS_AOW))[j] = f2bf(aow[j]);
  } else if (i < 49152) {
    int j = i - 32768; ((unsigned short*)(ws + WS_F1W))[j] = f2bf(f1w[j]);
  } else if (i < 65536) {
    int j = i - 49152; ((unsigned short*)(ws + WS_F2W))[j] = f2bf(f2w[j]);
  } else if (i < 67584) {
    int j = i - 65536; ((unsigned short*)(ws + WS_PW2))[j] = f2bf(pw2[j]);
  } else if (i < 67616) {
    int k = i - 67584;
    float s = png[k] * rsqrtf(pnv[k] + 1e-5f);
    float* w1f = (float*)(ws + WS_W1F);
    float* pbf = (float*)(ws + WS_PBF);
    w1f[k*3+0] = pw1[k*3+0] * s;
    w1f[k*3+1] = pw1[k*3+1] * s;
    w1f[k*3+2] = pw1[k*3+2] * s;
    pbf[k] = pnb[k] - pnm[k] * s;
  }
}

// ---------------- main fused kernel: 1 group / block, 2 waves, TOKEN-OWNED ----------------
// Wave w owns tokens [16w, 16w+16). Lane (lr,hi):
//   x[mi][r] = X[ch = mi*16 + hi*4 + r][tok = w*16 + lr],  mi = 0..3
// LN / Q / A2 / F / S are produced+consumed by own-wave rows -> no publish barriers.
// Only K and Vt cross waves -> 3 barriers per layer.
extern "C" __global__ __launch_bounds__(128, 2)
void nvt_mfma(const float* __restrict__ xyz,
              const float* __restrict__ new_xyz,
              const float* __restrict__ features,
              const int* __restrict__ group_idx,
              const unsigned char* __restrict__ empty_mask,
              const float* __restrict__ pos_b2,
              const float* __restrict__ ln1_g, const float* __restrict__ ln1_b,
              const float* __restrict__ qkv_b,
              const float* __restrict__ aob,
              const float* __restrict__ ln2_g, const float* __restrict__ ln2_b,
              const float* __restrict__ f1b,
              const float* __restrict__ f2b,
              const float* __restrict__ out_w, const float* __restrict__ out_b,
              const unsigned char* __restrict__ ws,
              float* __restrict__ out) {
  // LDS 18944B:
  //   S  @0     [32][72] bf16 (alias part f32[2][64] at end of kernel)
  //   Qb @4608  [32][72]      (alias A2; Fb[32][136] spans Qb+Kb)
  //   Kb @9216  [32][72]
  //   Vt @13824 [64][40]
  __shared__ __align__(16) unsigned char smem[18944];
  unsigned short* S  = (unsigned short*)smem;
  unsigned short* Qb = (unsigned short*)(smem + 4608);
  unsigned short* Kb = (unsigned short*)(smem + 9216);
  unsigned short* Fb = (unsigned short*)(smem + 4608);   // stride 136
  unsigned short* Vt = (unsigned short*)(smem + 13824);  // [64][40]
  float*          part = (float*)smem;                   // [2][64]
  unsigned short* A2 = Qb;

  const unsigned short* qkvw_b = (const unsigned short*)(ws + WS_QKV);
  const unsigned short* aow_b  = (const unsigned short*)(ws + WS_AOW);
  const unsigned short* f1w_b  = (const unsigned short*)(ws + WS_F1W);
  const unsigned short* f2w_b  = (const unsigned short*)(ws + WS_F2W);
  const unsigned short* w2b    = (const unsigned short*)(ws + WS_PW2);
  const float* w1f = (const float*)(ws + WS_W1F);
  const float* pbf = (const float*)(ws + WS_PBF);

  const int m    = blockIdx.x;
  const int tid  = threadIdx.x;
  const int w    = tid >> 6;       // wave 0/1
  const int lane = tid & 63;
  const int lr   = lane & 15;
  const int hi   = lane >> 4;
  const int tok  = w * 16 + lr;    // own token
  const bool empty = empty_mask[m] != 0;

  // ---- prologue: gather own token's features into x; compute own h in-register ----
  f32x4 x[4];
  bf16x8 bh;   // h B-fragment: h[tok][k=hi*8+0..7] -- exactly what this lane computes
  {
    int idx = group_idx[m * 32 + tok];
#pragma unroll
    for (int mi = 0; mi < 4; mi++)
      x[mi] = *(const f32x4*)(features + (size_t)idx * 64 + mi * 16 + hi * 4);
    float g0 = xyz[idx*3+0] - new_xyz[m*3+0];
    float g1 = xyz[idx*3+1] - new_xyz[m*3+1];
    float g2 = xyz[idx*3+2] - new_xyz[m*3+2];
    if (empty) {
      g0 = 0.f; g1 = 0.f; g2 = 0.f;
#pragma unroll
      for (int mi = 0; mi < 4; mi++) { x[mi][0]=0.f; x[mi][1]=0.f; x[mi][2]=0.f; x[mi][3]=0.f; }
    }
    float hf[8];
#pragma unroll
    for (int j = 0; j < 8; j++) {
      int k = hi * 8 + j;
      float hp = fmaf(g0, w1f[k*3+0], fmaf(g1, w1f[k*3+1], g2 * w1f[k*3+2])) + pbf[k];
      hf[j] = fmaxf(hp, 0.f);
    }
    bh = pack8(hf);
  }

  // ---- pos MLP layer 2 via MFMA: x += h @ w2^T + b2 (all 4 channel tiles) ----
#pragma unroll
  for (int mt = 0; mt < 4; mt++) {
    bf16x8 a = *(const bf16x8*)(w2b + (mt * 16 + lr) * 32 + hi * 8);
    float4 b4 = *(const float4*)(pos_b2 + mt * 16 + hi * 4);
    f32x4 bias; bias[0] = b4.x; bias[1] = b4.y; bias[2] = b4.z; bias[3] = b4.w;
    x[mt] += mfma16(a, bh, bias);
  }

  // LN: fully wave-internal (sum over hi lanes + mi regs); write own S rows. NO barrier.
  auto LN = [&](const float* g, const float* b) {
    float s = 0.f, s2 = 0.f;
#pragma unroll
    for (int mi = 0; mi < 4; mi++)
#pragma unroll
      for (int r = 0; r < 4; r++) { float v = x[mi][r]; s += v; s2 = fmaf(v, v, s2); }
    s  += __shfl_xor(s, 16);  s  += __shfl_xor(s, 32);
    s2 += __shfl_xor(s2, 16); s2 += __shfl_xor(s2, 32);
    float mu  = s * (1.f/64.f);
    float var = s2 * (1.f/64.f) - mu * mu;
    float inv = rsqrtf(fmaxf(var, 0.f) + 1e-5f);
#pragma unroll
    for (int mi = 0; mi < 4; mi++) {
      float4 g4 = *(const float4*)(g + mi * 16 + hi * 4);
      float4 b4 = *(const float4*)(b + mi * 16 + hi * 4);
      f32x4 o;
      o[0] = fmaf((x[mi][0] - mu) * inv, g4.x, b4.x);
      o[1] = fmaf((x[mi][1] - mu) * inv, g4.y, b4.y);
      o[2] = fmaf((x[mi][2] - mu) * inv, g4.z, b4.z);
      o[3] = fmaf((x[mi][3] - mu) * inv, g4.w, b4.w);
      *(bf16x4*)&S[tok * 72 + mi * 16 + hi * 4] = pack4(o);
    }
    cfence();   // S writes (bf16x4) precede own-row S reads (bf16x8) in next stage
  };

  // ---- transformer layers ----
  for (int ly = 0; ly < 2; ly++) {
    const unsigned short* Wq = qkvw_b + ly * 192 * 64;
    const float* Bq = qkv_b + ly * 192;

    LN(ly == 0 ? ln1_g : ln1_g + 64, ly == 0 ? ln1_b : ln1_b + 64);
    // (indexing kept explicit below for clarity)
    const float* l1g = ln1_g + ly * 64; (void)l1g;

    // qkv: Q,K as D[o][t own] (A=W all 8 tiles); V swapped D[t own][ch] (B=Wv all 4 tiles)
    {
      bf16x8 bs[2];
#pragma unroll
      for (int kt = 0; kt < 2; kt++)
        bs[kt] = *(const bf16x8*)&S[tok * 72 + kt * 32 + hi * 8];   // own rows (own-wave RAW)
      cfence();
#pragma unroll
      for (int mt = 0; mt < 8; mt++) {
        bf16x8 a0 = *(const bf16x8*)(Wq + (mt * 16 + lr) * 64 + hi * 8);
        bf16x8 a1 = *(const bf16x8*)(Wq + (mt * 16 + lr) * 64 + 32 + hi * 8);
        float4 b4 = *(const float4*)(Bq + mt * 16 + hi * 4);
        f32x4 acc; acc[0] = b4.x; acc[1] = b4.y; acc[2] = b4.z; acc[3] = b4.w;
        acc = mfma16(a0, bs[0], acc);
        acc = mfma16(a1, bs[1], acc);
        unsigned short* dst = (mt < 4) ? Qb : Kb;
        *(bf16x4*)&dst[tok * 72 + (mt & 3) * 16 + hi * 4] = pack4(acc);
      }
      // V swapped: acc[r] = V[tok2 = w*16 + hi*4 + r][ch = mtv*16 + lr]
#pragma unroll
      for (int mtv = 0; mtv < 4; mtv++) {
        bf16x8 b0 = *(const bf16x8*)(Wq + (128 + mtv * 16 + lr) * 64 + hi * 8);
        bf16x8 b1 = *(const bf16x8*)(Wq + (128 + mtv * 16 + lr) * 64 + 32 + hi * 8);
        float bv = Bq[128 + mtv * 16 + lr];
        f32x4 acc; acc[0] = bv; acc[1] = bv; acc[2] = bv; acc[3] = bv;
        acc = mfma16(bs[0], b0, acc);
        acc = mfma16(bs[1], b1, acc);
        *(bf16x4*)&Vt[(mtv * 16 + lr) * 40 + w * 16 + hi * 4] = pack4(acc);
      }
    }
    __syncthreads();   // barrier #1: publish K (all rows) and Vt (all columns)

    // ---- fused scores + softmax + PV (own i-tile = own tokens) ----
    {
      bf16x8 ak[2][2], bq[2], av[4];
#pragma unroll
      for (int jt = 0; jt < 2; jt++)
#pragma unroll
        for (int kt = 0; kt < 2; kt++)
          ak[jt][kt] = *(const bf16x8*)&Kb[(jt * 16 + lr) * 72 + kt * 32 + hi * 8];
#pragma unroll
      for (int kt = 0; kt < 2; kt++)
        bq[kt] = *(const bf16x8*)&Qb[tok * 72 + kt * 32 + hi * 8];
#pragma unroll
      for (int mt = 0; mt < 4; mt++)
        av[mt] = *(const bf16x8*)&Vt[(mt * 16 + lr) * 40 + hi * 8];
      cfence();   // pin reads above before A2 writes below (own-row WAR)

      // scores: p[jt][r] = P[j=jt*16+hi*4+r][i=tok]
      f32x4 p[2];
#pragma unroll
      for (int jt = 0; jt < 2; jt++) {
        f32x4 acc; acc[0] = 0.f; acc[1] = 0.f; acc[2] = 0.f; acc[3] = 0.f;
#pragma unroll
        for (int kt = 0; kt < 2; kt++) acc = mfma16(ak[jt][kt], bq[kt], acc);
        p[jt] = acc;
      }
      float mx = -3.4e38f;
#pragma unroll
      for (int jt = 0; jt < 2; jt++)
#pragma unroll
        for (int r = 0; r < 4; r++) { p[jt][r] *= 0.125f; mx = fmaxf(mx, p[jt][r]); }
      mx = fmaxf(mx, __shfl_xor(mx, 16));
      mx = fmaxf(mx, __shfl_xor(mx, 32));
      float sum = 0.f;
#pragma unroll
      for (int jt = 0; jt < 2; jt++)
#pragma unroll
        for (int r = 0; r < 4; r++) { float e = __expf(p[jt][r] - mx); p[jt][r] = e; sum += e; }
      sum += __shfl_xor(sum, 16);
      sum += __shfl_xor(sum, 32);
      float inv = 1.f / sum;

      // redistribute P to PV B-fragment layout via 8 shuffles (round-10-verified)
      unsigned u[2][2];
#pragma unroll
      for (int jt = 0; jt < 2; jt++) {
        u[jt][0] = pk2(p[jt][0] * inv, p[jt][1] * inv);
        u[jt][1] = pk2(p[jt][2] * inv, p[jt][3] * inv);
      }
      int s1 = lr + 32 * (hi & 1);
      int s2 = s1 + 16;
      unsigned c0 = __shfl(u[0][0], s1), c1 = __shfl(u[0][1], s1);
      unsigned d0 = __shfl(u[0][0], s2), d1 = __shfl(u[0][1], s2);
      unsigned e0 = __shfl(u[1][0], s1), e1 = __shfl(u[1][1], s1);
      unsigned f0 = __shfl(u[1][0], s2), f1 = __shfl(u[1][1], s2);
      bool sel = (hi >> 1) != 0;
      union { unsigned uu[4]; bf16x8 v; } bp;
      bp.uu[0] = sel ? e0 : c0;
      bp.uu[1] = sel ? e1 : c1;
      bp.uu[2] = sel ? f0 : d0;
      bp.uu[3] = sel ? f1 : d1;

      // PV -> A2[tok own][ch]
#pragma unroll
      for (int mt = 0; mt < 4; mt++) {
        f32x4 acc; acc[0] = 0.f; acc[1] = 0.f; acc[2] = 0.f; acc[3] = 0.f;
        acc = mfma16(av[mt], bp.v, acc);
        *(bf16x4*)&A2[tok * 72 + mt * 16 + hi * 4] = pack4(acc);
      }
      cfence();   // A2 writes precede own-row A2 reads in attn_out
    }

    // attn_out: x += A2 @ Wo^T + bo (B = A2 own rows; no barrier needed)
    {
      bf16x8 ba[2];
#pragma unroll
      for (int kt = 0; kt < 2; kt++)
        ba[kt] = *(const bf16x8*)&A2[tok * 72 + kt * 32 + hi * 8];
      cfence();
      const unsigned short* Wo = aow_b + ly * 64 * 64;
      const float* Bo = aob + ly * 64;
#pragma unroll
      for (int mt = 0; mt < 4; mt++) {
        bf16x8 a0 = *(const bf16x8*)(Wo + (mt * 16 + lr) * 64 + hi * 8);
        bf16x8 a1 = *(const bf16x8*)(Wo + (mt * 16 + lr) * 64 + 32 + hi * 8);
        float4 b4 = *(const float4*)(Bo + mt * 16 + hi * 4);
        f32x4 acc; acc[0] = b4.x; acc[1] = b4.y; acc[2] = b4.z; acc[3] = b4.w;
        acc = mfma16(a0, ba[0], acc);
        acc = mfma16(a1, ba[1], acc);
        x[mt] += acc;
      }
    }
    __syncthreads();   // barrier #2: all K/Vt/A2 cross-lane reads done before Fb overwrites Qb+Kb

    LN(ln2_g + ly*64, ln2_b + ly*64);

    // ff1: F[tok own][o] = relu(S @ W1^T + b1), all 8 output tiles
    {
      bf16x8 bs[2];
#pragma unroll
      for (int kt = 0; kt < 2; kt++)
        bs[kt] = *(const bf16x8*)&S[tok * 72 + kt * 32 + hi * 8];
      cfence();
      const unsigned short* W1 = f1w_b + ly * 128 * 64;
      const float* B1 = f1b + ly * 128;
#pragma unroll
      for (int mt = 0; mt < 8; mt++) {
        bf16x8 a0 = *(const bf16x8*)(W1 + (mt * 16 + lr) * 64 + hi * 8);
        bf16x8 a1 = *(const bf16x8*)(W1 + (mt * 16 + lr) * 64 + 32 + hi * 8);
        float4 b4 = *(const float4*)(B1 + mt * 16 + hi * 4);
        f32x4 acc; acc[0] = b4.x; acc[1] = b4.y; acc[2] = b4.z; acc[3] = b4.w;
        acc = mfma16(a0, bs[0], acc);
        acc = mfma16(a1, bs[1], acc);
#pragma unroll
        for (int r = 0; r < 4; r++) acc[r] = fmaxf(acc[r], 0.f);
        *(bf16x4*)&Fb[tok * 136 + mt * 16 + hi * 4] = pack4(acc);
      }
      cfence();   // F writes precede own-row F reads in ff2
    }

    // ff2: x += F @ W2^T + b2 (B = F own rows; no barrier)
    {
      bf16x8 bfr[4];
#pragma unroll
      for (int kt = 0; kt < 4; kt++)
        bfr[kt] = *(const bf16x8*)&Fb[tok * 136 + kt * 32 + hi * 8];
      cfence();
      const unsigned short* W2 = f2w_b + ly * 64 * 128;
      const float* B2 = f2b + ly * 64;
#pragma unroll
      for (int mt = 0; mt < 4; mt++) {
        float4 b4 = *(const float4*)(B2 + mt * 16 + hi * 4);
        f32x4 acc; acc[0] = b4.x; acc[1] = b4.y; acc[2] = b4.z; acc[3] = b4.w;
#pragma unroll
        for (int kt = 0; kt < 4; kt++) {
          bf16x8 a = *(const bf16x8*)(W2 + (mt * 16 + lr) * 128 + kt * 32 + hi * 8);
          acc = mfma16(a, bfr[kt], acc);
        }
        x[mt] += acc;
      }
    }
    __syncthreads();   // barrier #3: F reads done before next layer's K writes / part writes
  }

  // ---- max pool: reduce over own 16 tokens (lr axis), publish per-wave to part ----
  {
    f32x4 pm[4];
#pragma unroll
    for (int mi = 0; mi < 4; mi++) pm[mi] = x[mi];
#pragma unroll
    for (int d = 1; d < 16; d <<= 1)
#pragma unroll
      for (int mi = 0; mi < 4; mi++)
#pragma unroll
        for (int r = 0; r < 4; r++) pm[mi][r] = fmaxf(pm[mi][r], __shfl_xor(pm[mi][r], d));
    if (lr == 0) {
#pragma unroll
      for (int mi = 0; mi < 4; mi++)
        *(f32x4*)&part[w * 64 + mi * 16 + hi * 4] = pm[mi];
    }
  }
  __syncthreads();   // barrier #4: part published

  // ---- output projection: 128 outputs, one per thread (f32) ----
  {
    int o = tid;
    const float* wr = out_w + o * 64;
    float a0 = 0.f, a1 = 0.f, a2 = 0.f, a3 = 0.f;
#pragma unroll
    for (int i = 0; i < 16; i++) {
      float4 wv = *(const float4*)(wr + i * 4);
      float4 p0 = *(const float4*)&part[i * 4];
      float4 p1 = *(const float4*)&part[64 + i * 4];
      a0 = fmaf(fmaxf(p0.x, p1.x), wv.x, a0);
      a1 = fmaf(fmaxf(p0.y, p1.y), wv.y, a1);
      a2 = fmaf(fmaxf(p0.z, p1.z), wv.z, a2);
      a3 = fmaf(fmaxf(p0.w, p1.w), wv.w, a3);
    }
    out[(size_t)m * OUTD + o] = out_b[o] + (a0 + a1) + (a2 + a3);
  }
}

extern "C" void kernel_launch(void* const* d_in, const int* in_sizes, int n_in,
                              void* d_out, int out_size, void* d_ws, size_t ws_size,
                              hipStream_t stream) {
  const float* xyz         = (const float*)d_in[0];
  const float* new_xyz     = (const float*)d_in[1];
  const float* features    = (const float*)d_in[2];
  const int*   group_idx   = (const int*)d_in[3];
  const unsigned char* empty_mask = (const unsigned char*)d_in[4];
  const float* pos_w1      = (const float*)d_in[5];
  const float* pos_bn_g    = (const float*)d_in[6];
  const float* pos_bn_b    = (const float*)d_in[7];
  const float* pos_bn_mean = (const float*)d_in[8];
  const float* pos_bn_var  = (const float*)d_in[9];
  const float* pos_w2      = (const float*)d_in[10];
  const float* pos_b2      = (const float*)d_in[11];
  const float* ln1_g       = (const float*)d_in[12];
  const float* ln1_b       = (const float*)d_in[13];
  const float* qkv_w       = (const float*)d_in[14];
  const float* qkv_b       = (const float*)d_in[15];
  const float* aow         = (const float*)d_in[16];
  const float* aob         = (const float*)d_in[17];
  const float* ln2_g       = (const float*)d_in[18];
  const float* ln2_b       = (const float*)d_in[19];
  const float* f1w         = (const float*)d_in[20];
  const float* f1b         = (const float*)d_in[21];
  const float* f2w         = (const float*)d_in[22];
  const float* f2b         = (const float*)d_in[23];
  const float* out_w       = (const float*)d_in[24];
  const float* out_b       = (const float*)d_in[25];
  float* out = (float*)d_out;
  unsigned char* ws = (unsigned char*)d_ws;

  hipLaunchKernelGGL(convert_weights, dim3(265), dim3(256), 0, stream,
                     qkv_w, aow, f1w, f2w, pos_w2, pos_w1,
                     pos_bn_g, pos_bn_b, pos_bn_mean, pos_bn_var, ws);

  hipLaunchKernelGGL(nvt_mfma, dim3(MQ), dim3(128), 0, stream,
                     xyz, new_xyz, features, group_idx, empty_mask,
                     pos_b2, ln1_g, ln1_b, qkv_b, aob, ln2_g, ln2_b,
                     f1b, f2b, out_w, out_b, ws, out);
}

// Round 14
// 1409.857 us; speedup vs baseline: 1.7334x; 1.7334x over previous
//
#include <hip/hip_runtime.h>
#include <hip/hip_bf16.h>
#include <math.h>

#define MQ   65536
#define OUTD 128

typedef __attribute__((ext_vector_type(8))) short bf16x8;
typedef __attribute__((ext_vector_type(4))) short bf16x4;
typedef __attribute__((ext_vector_type(4))) float f32x4;

// ws byte offsets (bf16 weights + folded pos params)
#define WS_QKV   0        // 2*192*64 bf16 = 49152B
#define WS_AOW   49152    // 2*64*64       = 16384B
#define WS_F1W   65536    // 2*128*64      = 32768B
#define WS_F2W   98304    // 2*64*128      = 32768B
#define WS_PW2   131072   // 64*32         = 4096B
#define WS_W1F   135168   // 32*3 f32      = 384B
#define WS_PBF   135552   // 32 f32        = 128B

__device__ __forceinline__ unsigned short f2bf(float f) {
  unsigned u = __float_as_uint(f);
  u = (u + 0x7FFFu + ((u >> 16) & 1u)) >> 16;   // RTN
  return (unsigned short)u;
}

__device__ __forceinline__ f32x4 mfma16(bf16x8 a, bf16x8 b, f32x4 c) {
  return __builtin_amdgcn_mfma_f32_16x16x32_bf16(a, b, c, 0, 0, 0);
}

__device__ __forceinline__ unsigned pk2(float a, float b) {
  union { __hip_bfloat162 h; unsigned u; } c;
  float2 p; p.x = a; p.y = b;
  c.h = __float22bfloat162_rn(p);
  return c.u;
}

__device__ __forceinline__ bf16x4 pack4(f32x4 v) {
  union { unsigned u[2]; bf16x4 s; } c;
  c.u[0] = pk2(v[0], v[1]);
  c.u[1] = pk2(v[2], v[3]);
  return c.s;
}

__device__ __forceinline__ bf16x8 pack8(const float* v) {
  union { unsigned u[4]; bf16x8 s; } c;
#pragma unroll
  for (int i = 0; i < 4; i++) c.u[i] = pk2(v[2*i], v[2*i+1]);
  return c.s;
}

// Opaque compiler fence: pins LDS reads above / writes below (same-wave WAR in fused stage).
__device__ __forceinline__ void cfence() { asm volatile("" ::: "memory"); }

// ---------------- weight conversion prologue (unchanged, round-2-verified) ----------------
extern "C" __global__ __launch_bounds__(256)
void convert_weights(const float* __restrict__ qkv_w, const float* __restrict__ aow,
                     const float* __restrict__ f1w,  const float* __restrict__ f2w,
                     const float* __restrict__ pw2,  const float* __restrict__ pw1,
                     const float* __restrict__ png,  const float* __restrict__ pnb,
                     const float* __restrict__ pnm,  const float* __restrict__ pnv,
                     unsigned char* __restrict__ ws) {
  int i = blockIdx.x * 256 + threadIdx.x;
  if (i < 24576) {
    ((unsigned short*)(ws + WS_QKV))[i] = f2bf(qkv_w[i]);
  } else if (i < 32768) {
    int j = i - 24576; ((unsigned short*)(ws + WS_AOW))[j] = f2bf(aow[j]);
  } else if (i < 49152) {
    int j = i - 32768; ((unsigned short*)(ws + WS_F1W))[j] = f2bf(f1w[j]);
  } else if (i < 65536) {
    int j = i - 49152; ((unsigned short*)(ws + WS_F2W))[j] = f2bf(f2w[j]);
  } else if (i < 67584) {
    int j = i - 65536; ((unsigned short*)(ws + WS_PW2))[j] = f2bf(pw2[j]);
  } else if (i < 67616) {
    int k = i - 67584;
    float s = png[k] * rsqrtf(pnv[k] + 1e-5f);
    float* w1f = (float*)(ws + WS_W1F);
    float* pbf = (float*)(ws + WS_PBF);
    w1f[k*3+0] = pw1[k*3+0] * s;
    w1f[k*3+1] = pw1[k*3+1] * s;
    w1f[k*3+2] = pw1[k*3+2] * s;
    pbf[k] = pnb[k] - pnm[k] * s;
  }
}

// ---------------- main fused kernel: 1 group / block, 2 waves, residual x in registers ----------------
// x[nt][mi][r] = X[ch = (w+mi*2)*16 + hi*4 + r][tok = nt*16 + lr]
// (round-10 structure = session best 1408us; this round adds only s_setprio(1)
// around MFMA clusters — T5: 8 independent blocks/CU are at uncorrelated stages,
// so boosting MFMA-phase waves can win arbitration over other blocks' load phases)
extern "C" __global__ __launch_bounds__(128, 2)
void nvt_mfma(const float* __restrict__ xyz,
              const float* __restrict__ new_xyz,
              const float* __restrict__ features,
              const int* __restrict__ group_idx,
              const unsigned char* __restrict__ empty_mask,
              const float* __restrict__ pos_b2,
              const float* __restrict__ ln1_g, const float* __restrict__ ln1_b,
              const float* __restrict__ qkv_b,
              const float* __restrict__ aob,
              const float* __restrict__ ln2_g, const float* __restrict__ ln2_b,
              const float* __restrict__ f1b,
              const float* __restrict__ f2b,
              const float* __restrict__ out_w, const float* __restrict__ out_b,
              const unsigned char* __restrict__ ws,
              float* __restrict__ out) {
  // LDS 18944B:
  //   S  @0     [32][72] bf16 (alias Hs[32][40], part f32[2][64])
  //   Qb @4608  [32][72]      (alias A2; Fb[32][136] spans Qb+Kb)
  //   Kb @9216  [32][72]
  //   Vt @13824 [64][40]      (alias lnbuf f32[2][32][2] in first 512B)
  __shared__ __align__(16) unsigned char smem[18944];
  unsigned short* S  = (unsigned short*)smem;
  unsigned short* Qb = (unsigned short*)(smem + 4608);
  unsigned short* Kb = (unsigned short*)(smem + 9216);
  unsigned short* Fb = (unsigned short*)(smem + 4608);   // stride 136
  unsigned short* Vt = (unsigned short*)(smem + 13824);  // [64][40]
  unsigned short* Hs = S;                                // h staging [32][40]
  float*          part  = (float*)smem;                  // [2][64]
  float*          lnbuf = (float*)(smem + 13824);        // [2][32][2]
  unsigned short* A2 = Qb;

  const unsigned short* qkvw_b = (const unsigned short*)(ws + WS_QKV);
  const unsigned short* aow_b  = (const unsigned short*)(ws + WS_AOW);
  const unsigned short* f1w_b  = (const unsigned short*)(ws + WS_F1W);
  const unsigned short* f2w_b  = (const unsigned short*)(ws + WS_F2W);
  const unsigned short* w2b    = (const unsigned short*)(ws + WS_PW2);
  const float* w1f = (const float*)(ws + WS_W1F);
  const float* pbf = (const float*)(ws + WS_PBF);

  const int m    = blockIdx.x;
  const int tid  = threadIdx.x;
  const int w    = tid >> 6;       // wave 0/1
  const int lane = tid & 63;
  const int lr   = lane & 15;
  const int hi   = lane >> 4;
  const bool empty = empty_mask[m] != 0;

  // ---- stage A: h -> Hs ; gather features into x registers ----
  {
    int t = tid & 31, kb = tid >> 5;
    int idx = group_idx[m * 32 + t];
    float g0 = xyz[idx*3+0] - new_xyz[m*3+0];
    float g1 = xyz[idx*3+1] - new_xyz[m*3+1];
    float g2 = xyz[idx*3+2] - new_xyz[m*3+2];
    if (empty) { g0 = 0.f; g1 = 0.f; g2 = 0.f; }
    float hf[8];
#pragma unroll
    for (int j = 0; j < 8; j++) {
      int k = kb * 8 + j;
      float hp = fmaf(g0, w1f[k*3+0], fmaf(g1, w1f[k*3+1], g2 * w1f[k*3+2])) + pbf[k];
      hf[j] = fmaxf(hp, 0.f);
    }
    *(bf16x8*)&Hs[t * 40 + kb * 8] = pack8(hf);
  }
  f32x4 x[2][2];
  {
    int tg[2];
    tg[0] = group_idx[m * 32 + lr];
    tg[1] = group_idx[m * 32 + 16 + lr];
#pragma unroll
    for (int nt = 0; nt < 2; nt++)
#pragma unroll
      for (int mi = 0; mi < 2; mi++) {
        int mt = w + mi * 2;
        x[nt][mi] = *(const f32x4*)(features + (size_t)tg[nt] * 64 + mt * 16 + hi * 4);
      }
    if (empty) {
#pragma unroll
      for (int nt = 0; nt < 2; nt++)
#pragma unroll
        for (int mi = 0; mi < 2; mi++) { x[nt][mi][0]=0.f; x[nt][mi][1]=0.f; x[nt][mi][2]=0.f; x[nt][mi][3]=0.f; }
    }
  }
  __syncthreads();

  // ---- pos MLP layer 2 via MFMA: x += h @ w2^T + b2 ----
  {
    bf16x8 bh[2];
#pragma unroll
    for (int nt = 0; nt < 2; nt++)
      bh[nt] = *(const bf16x8*)&Hs[(nt * 16 + lr) * 40 + hi * 8];
    __builtin_amdgcn_s_setprio(1);
#pragma unroll
    for (int mi = 0; mi < 2; mi++) {
      int mt = w + mi * 2;
      bf16x8 a = *(const bf16x8*)(w2b + (mt * 16 + lr) * 32 + hi * 8);
      float4 b4 = *(const float4*)(pos_b2 + mt * 16 + hi * 4);
      f32x4 bias; bias[0] = b4.x; bias[1] = b4.y; bias[2] = b4.z; bias[3] = b4.w;
#pragma unroll
      for (int nt = 0; nt < 2; nt++) x[nt][mi] += mfma16(a, bh[nt], bias);
    }
    __builtin_amdgcn_s_setprio(0);
  }
  // (no barrier here: LN's publish barrier below provides the WAR protection)

  // LN: x regs -> S (bf16), cross-wave partial-sum exchange through lnbuf
  auto LN = [&](const float* g, const float* b) {
    float s[2], s2[2];
#pragma unroll
    for (int nt = 0; nt < 2; nt++) {
      float a = 0.f, a2 = 0.f;
#pragma unroll
      for (int mi = 0; mi < 2; mi++)
#pragma unroll
        for (int r = 0; r < 4; r++) { float v = x[nt][mi][r]; a += v; a2 = fmaf(v, v, a2); }
      a  += __shfl_xor(a, 16);  a  += __shfl_xor(a, 32);
      a2 += __shfl_xor(a2, 16); a2 += __shfl_xor(a2, 32);
      s[nt] = a; s2[nt] = a2;
    }
    if (hi == 0) {
#pragma unroll
      for (int nt = 0; nt < 2; nt++) {
        int tok = nt * 16 + lr;
        lnbuf[w * 64 + tok * 2 + 0] = s[nt];
        lnbuf[w * 64 + tok * 2 + 1] = s2[nt];
      }
    }
    __syncthreads();
#pragma unroll
    for (int nt = 0; nt < 2; nt++) {
      int tok = nt * 16 + lr;
      float st  = s[nt]  + lnbuf[(1 - w) * 64 + tok * 2 + 0];
      float s2t = s2[nt] + lnbuf[(1 - w) * 64 + tok * 2 + 1];
      float mu  = st * (1.f/64.f);
      float var = s2t * (1.f/64.f) - mu * mu;
      float inv = rsqrtf(fmaxf(var, 0.f) + 1e-5f);
#pragma unroll
      for (int mi = 0; mi < 2; mi++) {
        int mt = w + mi * 2;
        float4 g4 = *(const float4*)(g + mt * 16 + hi * 4);
        float4 b4 = *(const float4*)(b + mt * 16 + hi * 4);
        f32x4 o;
        o[0] = fmaf((x[nt][mi][0] - mu) * inv, g4.x, b4.x);
        o[1] = fmaf((x[nt][mi][1] - mu) * inv, g4.y, b4.y);
        o[2] = fmaf((x[nt][mi][2] - mu) * inv, g4.z, b4.z);
        o[3] = fmaf((x[nt][mi][3] - mu) * inv, g4.w, b4.w);
        *(bf16x4*)&S[tok * 72 + mt * 16 + hi * 4] = pack4(o);
      }
    }
    __syncthreads();
  };

  // ---- transformer layers ----
  for (int ly = 0; ly < 2; ly++) {
    LN(ln1_g + ly*64, ln1_b + ly*64);

    // qkv: Q,K as D[o][t] (A=W rows); V swapped as D[t][o] (A=S rows) -> packed Vt store
    {
      bf16x8 bs[2][2];
#pragma unroll
      for (int nt = 0; nt < 2; nt++)
#pragma unroll
        for (int kt = 0; kt < 2; kt++)
          bs[nt][kt] = *(const bf16x8*)&S[(nt * 16 + lr) * 72 + kt * 32 + hi * 8];
      const unsigned short* Wq = qkvw_b + ly * 192 * 64;
      const float* Bq = qkv_b + ly * 192;
      __builtin_amdgcn_s_setprio(1);
#pragma unroll
      for (int mi = 0; mi < 4; mi++) {
        int mt = w + mi * 2;
        bf16x8 a[2];
#pragma unroll
        for (int kt = 0; kt < 2; kt++)
          a[kt] = *(const bf16x8*)(Wq + (mt * 16 + lr) * 64 + kt * 32 + hi * 8);
        float4 b4 = *(const float4*)(Bq + mt * 16 + hi * 4);
#pragma unroll
        for (int nt = 0; nt < 2; nt++) {
          f32x4 acc; acc[0] = b4.x; acc[1] = b4.y; acc[2] = b4.z; acc[3] = b4.w;
#pragma unroll
          for (int kt = 0; kt < 2; kt++) acc = mfma16(a[kt], bs[nt][kt], acc);
          int t = nt * 16 + lr;
          unsigned short* dst = (mt < 4) ? Qb : Kb;
          *(bf16x4*)&dst[t * 72 + (mt & 3) * 16 + hi * 4] = pack4(acc);
        }
      }
      // V swapped: acc[r] = V[tok=nt*16+hi*4+r][ch=mtv*16+lr]
#pragma unroll
      for (int mvi = 0; mvi < 2; mvi++) {
        int mtv = w + mvi * 2;
        bf16x8 b0 = *(const bf16x8*)(Wq + (128 + mtv * 16 + lr) * 64 + hi * 8);
        bf16x8 b1 = *(const bf16x8*)(Wq + (128 + mtv * 16 + lr) * 64 + 32 + hi * 8);
        float bv = Bq[128 + mtv * 16 + lr];
#pragma unroll
        for (int nt = 0; nt < 2; nt++) {
          f32x4 acc; acc[0] = bv; acc[1] = bv; acc[2] = bv; acc[3] = bv;
          acc = mfma16(bs[nt][0], b0, acc);
          acc = mfma16(bs[nt][1], b1, acc);
          *(bf16x4*)&Vt[(mtv * 16 + lr) * 40 + nt * 16 + hi * 4] = pack4(acc);
        }
      }
      __builtin_amdgcn_s_setprio(0);
    }
    __syncthreads();

    // ---- fused scores + softmax + PV (wave-local; own i-tile = own token-tile w) ----
    {
      bf16x8 ak[2][2], bq[2], av[4];
#pragma unroll
      for (int jt = 0; jt < 2; jt++)
#pragma unroll
        for (int kt = 0; kt < 2; kt++)
          ak[jt][kt] = *(const bf16x8*)&Kb[(jt * 16 + lr) * 72 + kt * 32 + hi * 8];
#pragma unroll
      for (int kt = 0; kt < 2; kt++)
        bq[kt] = *(const bf16x8*)&Qb[(w * 16 + lr) * 72 + kt * 32 + hi * 8];
#pragma unroll
      for (int mt = 0; mt < 4; mt++)
        av[mt] = *(const bf16x8*)&Vt[(mt * 16 + lr) * 40 + hi * 8];
      cfence();   // pin reads above before A2 writes below (own-row WAR; LDS in-order per wave)

      // scores: p[jt][r] = P[j=jt*16+hi*4+r][i=w*16+lr]
      __builtin_amdgcn_s_setprio(1);
      f32x4 p[2];
#pragma unroll
      for (int jt = 0; jt < 2; jt++) {
        f32x4 acc; acc[0] = 0.f; acc[1] = 0.f; acc[2] = 0.f; acc[3] = 0.f;
#pragma unroll
        for (int kt = 0; kt < 2; kt++) acc = mfma16(ak[jt][kt], bq[kt], acc);
        p[jt] = acc;
      }
      __builtin_amdgcn_s_setprio(0);
      float mx = -3.4e38f;
#pragma unroll
      for (int jt = 0; jt < 2; jt++)
#pragma unroll
        for (int r = 0; r < 4; r++) { p[jt][r] *= 0.125f; mx = fmaxf(mx, p[jt][r]); }
      mx = fmaxf(mx, __shfl_xor(mx, 16));
      mx = fmaxf(mx, __shfl_xor(mx, 32));
      float sum = 0.f;
#pragma unroll
      for (int jt = 0; jt < 2; jt++)
#pragma unroll
        for (int r = 0; r < 4; r++) { float e = __expf(p[jt][r] - mx); p[jt][r] = e; sum += e; }
      sum += __shfl_xor(sum, 16);
      sum += __shfl_xor(sum, 32);
      float inv = 1.f / sum;

      // pack P (bf16) and redistribute to PV B-fragment layout via 8 shuffles:
      // target lane (lr,hi) needs P[j=hi*8+jj][i=w*16+lr]; source jt=hi>>1, hi'=2(hi&1)+(jj>>2).
      unsigned u[2][2];
#pragma unroll
      for (int jt = 0; jt < 2; jt++) {
        u[jt][0] = pk2(p[jt][0] * inv, p[jt][1] * inv);
        u[jt][1] = pk2(p[jt][2] * inv, p[jt][3] * inv);
      }
      int s1 = lr + 32 * (hi & 1);   // lane (lr, hi'=2*(hi&1))
      int s2 = s1 + 16;              // lane (lr, hi'+1)
      unsigned c0 = __shfl(u[0][0], s1), c1 = __shfl(u[0][1], s1);
      unsigned d0 = __shfl(u[0][0], s2), d1 = __shfl(u[0][1], s2);
      unsigned e0 = __shfl(u[1][0], s1), e1 = __shfl(u[1][1], s1);
      unsigned f0 = __shfl(u[1][0], s2), f1 = __shfl(u[1][1], s2);
      bool sel = (hi >> 1) != 0;
      union { unsigned uu[4]; bf16x8 v; } bp;
      bp.uu[0] = sel ? e0 : c0;
      bp.uu[1] = sel ? e1 : c1;
      bp.uu[2] = sel ? f0 : d0;
      bp.uu[3] = sel ? f1 : d1;

      // PV: D[ch][tok own tile] = mfma(Vt rows, bp) -> A2[tok][ch], rows w*16+lr (wave-disjoint)
      __builtin_amdgcn_s_setprio(1);
#pragma unroll
      for (int mt = 0; mt < 4; mt++) {
        f32x4 acc; acc[0] = 0.f; acc[1] = 0.f; acc[2] = 0.f; acc[3] = 0.f;
        acc = mfma16(av[mt], bp.v, acc);
        *(bf16x4*)&A2[(w * 16 + lr) * 72 + mt * 16 + hi * 4] = pack4(acc);
      }
      __builtin_amdgcn_s_setprio(0);
    }
    __syncthreads();

    // attn_out: x += A2 @ Wao^T + b (accumulate in registers)
    {
      bf16x8 ba[2][2];
#pragma unroll
      for (int nt = 0; nt < 2; nt++)
#pragma unroll
        for (int kt = 0; kt < 2; kt++)
          ba[nt][kt] = *(const bf16x8*)&A2[(nt * 16 + lr) * 72 + kt * 32 + hi * 8];
      const unsigned short* Wo = aow_b + ly * 64 * 64;
      const float* Bo = aob + ly * 64;
      __builtin_amdgcn_s_setprio(1);
#pragma unroll
      for (int mi = 0; mi < 2; mi++) {
        int mt = w + mi * 2;
        bf16x8 a[2];
#pragma unroll
        for (int kt = 0; kt < 2; kt++)
          a[kt] = *(const bf16x8*)(Wo + (mt * 16 + lr) * 64 + kt * 32 + hi * 8);
        float4 b4 = *(const float4*)(Bo + mt * 16 + hi * 4);
#pragma unroll
        for (int nt = 0; nt < 2; nt++) {
          f32x4 acc; acc[0] = b4.x; acc[1] = b4.y; acc[2] = b4.z; acc[3] = b4.w;
#pragma unroll
          for (int kt = 0; kt < 2; kt++) acc = mfma16(a[kt], ba[nt][kt], acc);
          x[nt][mi] += acc;
        }
      }
      __builtin_amdgcn_s_setprio(0);
    }
    // (no barrier: LN2's publish barrier protects A2 reads; next Qb writer is ff1 after LN2b)

    LN(ln2_g + ly*64, ln2_b + ly*64);

    // ff1: F[t][o] = relu(S @ W1^T + b1), o<128
    {
      bf16x8 bs[2][2];
#pragma unroll
      for (int nt = 0; nt < 2; nt++)
#pragma unroll
        for (int kt = 0; kt < 2; kt++)
          bs[nt][kt] = *(const bf16x8*)&S[(nt * 16 + lr) * 72 + kt * 32 + hi * 8];
      const unsigned short* W1 = f1w_b + ly * 128 * 64;
      const float* B1 = f1b + ly * 128;
      __builtin_amdgcn_s_setprio(1);
#pragma unroll
      for (int mi = 0; mi < 4; mi++) {
        int mt = w + mi * 2;
        bf16x8 a[2];
#pragma unroll
        for (int kt = 0; kt < 2; kt++)
          a[kt] = *(const bf16x8*)(W1 + (mt * 16 + lr) * 64 + kt * 32 + hi * 8);
        float4 b4 = *(const float4*)(B1 + mt * 16 + hi * 4);
#pragma unroll
        for (int nt = 0; nt < 2; nt++) {
          f32x4 acc; acc[0] = b4.x; acc[1] = b4.y; acc[2] = b4.z; acc[3] = b4.w;
#pragma unroll
          for (int kt = 0; kt < 2; kt++) acc = mfma16(a[kt], bs[nt][kt], acc);
#pragma unroll
          for (int r = 0; r < 4; r++) acc[r] = fmaxf(acc[r], 0.f);
          *(bf16x4*)&Fb[(nt * 16 + lr) * 136 + mt * 16 + hi * 4] = pack4(acc);
        }
      }
      __builtin_amdgcn_s_setprio(0);
    }
    __syncthreads();

    // ff2: x += F @ W2^T + b2 (accumulate in registers)
    {
      bf16x8 bfr[2][4];
#pragma unroll
      for (int nt = 0; nt < 2; nt++)
#pragma unroll
        for (int kt = 0; kt < 4; kt++)
          bfr[nt][kt] = *(const bf16x8*)&Fb[(nt * 16 + lr) * 136 + kt * 32 + hi * 8];
      const unsigned short* W2 = f2w_b + ly * 64 * 128;
      const float* B2 = f2b + ly * 64;
      __builtin_amdgcn_s_setprio(1);
#pragma unroll
      for (int mi = 0; mi < 2; mi++) {
        int mt = w + mi * 2;
        bf16x8 a[4];
#pragma unroll
        for (int kt = 0; kt < 4; kt++)
          a[kt] = *(const bf16x8*)(W2 + (mt * 16 + lr) * 128 + kt * 32 + hi * 8);
        float4 b4 = *(const float4*)(B2 + mt * 16 + hi * 4);
#pragma unroll
        for (int nt = 0; nt < 2; nt++) {
          f32x4 acc; acc[0] = b4.x; acc[1] = b4.y; acc[2] = b4.z; acc[3] = b4.w;
#pragma unroll
          for (int kt = 0; kt < 4; kt++) acc = mfma16(a[kt], bfr[nt][kt], acc);
          x[nt][mi] += acc;
        }
      }
      __builtin_amdgcn_s_setprio(0);
    }
    // (no barrier: next LN1's publish barrier protects F reads; after last layer only reg ops)
  }

  // ---- max pool over tokens: register shuffle tree ----
  {
    f32x4 pm[2];
#pragma unroll
    for (int mi = 0; mi < 2; mi++)
#pragma unroll
      for (int r = 0; r < 4; r++) pm[mi][r] = fmaxf(x[0][mi][r], x[1][mi][r]);
#pragma unroll
    for (int d = 1; d < 16; d <<= 1)
#pragma unroll
      for (int mi = 0; mi < 2; mi++)
#pragma unroll
        for (int r = 0; r < 4; r++) pm[mi][r] = fmaxf(pm[mi][r], __shfl_xor(pm[mi][r], d));
    if (lr == 0) {
#pragma unroll
      for (int mi = 0; mi < 2; mi++) {
        int mt = w + mi * 2;
        *(f32x4*)&part[mt * 16 + hi * 4] = pm[mi];
      }
    }
  }
  __syncthreads();

  // ---- output projection: 128 outputs, one per thread (f32) ----
  {
    int o = tid;
    const float* wr = out_w + o * 64;
    float a0 = 0.f, a1 = 0.f, a2 = 0.f, a3 = 0.f;
#pragma unroll
    for (int i = 0; i < 16; i++) {
      float4 wv = *(const float4*)(wr + i * 4);
      float4 pv = *(const float4*)&part[i * 4];
      a0 = fmaf(pv.x, wv.x, a0);
      a1 = fmaf(pv.y, wv.y, a1);
      a2 = fmaf(pv.z, wv.z, a2);
      a3 = fmaf(pv.w, wv.w, a3);
    }
    out[(size_t)m * OUTD + o] = out_b[o] + (a0 + a1) + (a2 + a3);
  }
}

extern "C" void kernel_launch(void* const* d_in, const int* in_sizes, int n_in,
                              void* d_out, int out_size, void* d_ws, size_t ws_size,
                              hipStream_t stream) {
  const float* xyz         = (const float*)d_in[0];
  const float* new_xyz     = (const float*)d_in[1];
  const float* features    = (const float*)d_in[2];
  const int*   group_idx   = (const int*)d_in[3];
  const unsigned char* empty_mask = (const unsigned char*)d_in[4];
  const float* pos_w1      = (const float*)d_in[5];
  const float* pos_bn_g    = (const float*)d_in[6];
  const float* pos_bn_b    = (const float*)d_in[7];
  const float* pos_bn_mean = (const float*)d_in[8];
  const float* pos_bn_var  = (const float*)d_in[9];
  const float* pos_w2      = (const float*)d_in[10];
  const float* pos_b2      = (const float*)d_in[11];
  const float* ln1_g       = (const float*)d_in[12];
  const float* ln1_b       = (const float*)d_in[13];
  const float* qkv_w       = (const float*)d_in[14];
  const float* qkv_b       = (const float*)d_in[15];
  const float* aow         = (const float*)d_in[16];
  const float* aob         = (const float*)d_in[17];
  const float* ln2_g       = (const float*)d_in[18];
  const float* ln2_b       = (const float*)d_in[19];
  const float* f1w         = (const float*)d_in[20];
  const float* f1b         = (const float*)d_in[21];
  const float* f2w         = (const float*)d_in[22];
  const float* f2b         = (const float*)d_in[23];
  const float* out_w       = (const float*)d_in[24];
  const float* out_b       = (const float*)d_in[25];
  float* out = (float*)d_out;
  unsigned char* ws = (unsigned char*)d_ws;

  hipLaunchKernelGGL(convert_weights, dim3(265), dim3(256), 0, stream,
                     qkv_w, aow, f1w, f2w, pos_w2, pos_w1,
                     pos_bn_g, pos_bn_b, pos_bn_mean, pos_bn_var, ws);

  hipLaunchKernelGGL(nvt_mfma, dim3(MQ), dim3(128), 0, stream,
                     xyz, new_xyz, features, group_idx, empty_mask,
                     pos_b2, ln1_g, ln1_b, qkv_b, aob, ln2_g, ln2_b,
                     f1b, f2b, out_w, out_b, ws, out);
}